// Round 1
// baseline (1561.727 us; speedup 1.0000x reference)
//
#include <hip/hip_runtime.h>

// GCN (4 layers, DIM=128) + concepts + EntropyLinear + log_softmax over nodes.
// R7: ONE persistent mega-kernel. Previous 18-kernel pipeline was dispatch-
//     overhead-bound (~10us/launch * 18 vs ~70us of roofline work). All phases
//     now run in a single <<<1024, 256>>> launch with software grid barriers
//     (agent-scope atomics; 4 blocks/CU co-residency guaranteed by
//     __launch_bounds__(256,4) + 32KB LDS). Block-stride item loops keep the
//     slice = bid&3 XCD/L2 locality of the aggregation phases intact.

#define DIMF 128
#define GRID 1024
#define TPB  256

typedef __bf16 bf16x8 __attribute__((ext_vector_type(8)));
typedef float f32x4 __attribute__((ext_vector_type(4)));

static __device__ __forceinline__ ushort f2bf(float f) {
    uint u = __float_as_uint(f);
    u += 0x7fffu + ((u >> 16) & 1u);     // round-nearest-even
    return (ushort)(u >> 16);
}
static __device__ __forceinline__ float bflo(uint u) { return __uint_as_float(u << 16); }
static __device__ __forceinline__ float bfhi(uint u) { return __uint_as_float(u & 0xffff0000u); }

static __device__ __forceinline__ void upadd(float* acc, const int4& u) {
    const uint* w = (const uint*)&u;
#pragma unroll
    for (int k = 0; k < 4; ++k) {
        acc[2 * k]     += bflo(w[k]);
        acc[2 * k + 1] += bfhi(w[k]);
    }
}

// ---------------- LDS union (32 KB; 4 blocks/CU = 128 KB of 160 KB) ---------

union SMem {
    ushort ws[16384];                                    // gemm W tile (32 KB)
    struct { int h[256]; } ha;                           // histA
    struct { int tmp[256]; } sc;                         // scanNB
    struct { int h[256]; int lb[256]; } sa;              // scatA
    struct { int cnt[256]; int cur[256]; int tmp[256]; } pb;  // phaseB
    struct { float wcT[1280]; float lb[16]; } ep;        // epilogue
    struct { float2 red[4]; } r1;                        // lsm1
    struct { float red[2]; } wc;                         // wcomb
    float Ls[16];                                        // lsm3
};

// ---------------- software grid barrier (all 1024 blocks co-resident) -------
// Monotonic counter; release flushes XCD L2 (buffer_wbl2), acquire invalidates
// (buffer_inv) -- correct across non-coherent per-XCD L2s.

static __device__ __forceinline__ void gsync(uint* cnt, uint target) {
    __syncthreads();   // drains vmcnt/lgkmcnt: block's writes are in L2
    if (threadIdx.x == 0) {
        __hip_atomic_fetch_add(cnt, 1u, __ATOMIC_RELEASE, __HIP_MEMORY_SCOPE_AGENT);
        while (__hip_atomic_load(cnt, __ATOMIC_RELAXED, __HIP_MEMORY_SCOPE_AGENT) < target)
            __builtin_amdgcn_s_sleep(2);
        (void)__hip_atomic_load(cnt, __ATOMIC_ACQUIRE, __HIP_MEMORY_SCOPE_AGENT);
    }
    __syncthreads();
}

// ---------------- GEMM helpers (forceinline so LDS addrspace is inferred) ---

static __device__ __forceinline__ void ldws(ushort* ws, const ushort* WTsL, int tid) {
    const int4* src = (const int4*)WTsL;
    int4* dst = (int4*)ws;
#pragma unroll
    for (int i = 0; i < 8; ++i) dst[tid + 256 * i] = src[tid + 256 * i];
}

static __device__ __forceinline__ void mfma_store(const ushort* ws, const int4* a,
        const float* dis, ushort* M, int nrows, int it, int tid) {
    int wave = tid >> 6, lane = tid & 63;
    int lo = lane & 15, hi = lane >> 4;
    f32x4 acc[8];
#pragma unroll
    for (int ct = 0; ct < 8; ++ct) acc[ct] = (f32x4){0.f, 0.f, 0.f, 0.f};
#pragma unroll
    for (int kc = 0; kc < 4; ++kc) {
        bf16x8 av = __builtin_bit_cast(bf16x8, a[kc]);
#pragma unroll
        for (int ct = 0; ct < 8; ++ct) {
            int col = ct * 16 + lo;
            int byte = (col * 256 + kc * 64 + hi * 16) ^ ((col & 7) << 4);
            bf16x8 bv = *(const bf16x8*)((const char*)ws + byte);
            acc[ct] = __builtin_amdgcn_mfma_f32_16x16x32_bf16(av, bv, acc[ct], 0, 0, 0);
        }
    }
    int rbase = it * 64 + wave * 16 + hi * 4;
#pragma unroll
    for (int r = 0; r < 4; ++r) {
        int orow = rbase + r;
        if (orow < nrows) {
            float dn = dis[orow];
#pragma unroll
            for (int ct = 0; ct < 8; ++ct)
                M[((size_t)(ct >> 1) * nrows + orow) * 32 + (ct & 1) * 16 + lo]
                    = f2bf(dn * acc[ct][r]);
        }
    }
}

static __device__ __forceinline__ void gemm_phase(ushort* ws, const ushort* H,
        const ushort* WTsL, const float* dis, ushort* M, int n, int bid, int tid) {
    int nI = (n + 63) >> 6;
    for (int it = bid; it < nI; it += GRID) {
        __syncthreads();                 // prev item's ws reads done
        ldws(ws, WTsL, tid);
        int wave = tid >> 6, lane = tid & 63;
        int lo = lane & 15, hi = lane >> 4;
        int arow = it * 64 + wave * 16 + lo;
        bool inb = arow < n;
        int4 a[4];
        const int4* h4 = (const int4*)H;    // sliced: [slice][node][4 x int4]
#pragma unroll
        for (int kc = 0; kc < 4; ++kc) {
            int4 z = {0, 0, 0, 0};
            a[kc] = inb ? h4[((size_t)kc * n + arow) * 4 + hi] : z;
        }
        __syncthreads();
        mfma_store(ws, a, dis, M, n, it, tid);
    }
}

static __device__ __forceinline__ void gemm0_phase(ushort* ws, const float* X,
        const ushort* WTsL, const float* dis, ushort* M, int n, int bid, int tid) {
    int nI = (n + 63) >> 6;
    for (int it = bid; it < nI; it += GRID) {
        __syncthreads();
        ldws(ws, WTsL, tid);
        int wave = tid >> 6, lane = tid & 63;
        int lo = lane & 15, hi = lane >> 4;
        int arow = it * 64 + wave * 16 + lo;
        bool inb = arow < n;
        int4 a[4];
        const float4* x4 = (const float4*)X;
#pragma unroll
        for (int kc = 0; kc < 4; ++kc) {
            float4 f0 = make_float4(0.f, 0.f, 0.f, 0.f), f1 = f0;
            if (inb) {
                f0 = x4[(size_t)arow * 32 + kc * 8 + hi * 2];
                f1 = x4[(size_t)arow * 32 + kc * 8 + hi * 2 + 1];
            }
            ushort u[8] = { f2bf(f0.x), f2bf(f0.y), f2bf(f0.z), f2bf(f0.w),
                            f2bf(f1.x), f2bf(f1.y), f2bf(f1.z), f2bf(f1.w) };
            a[kc] = *(const int4*)u;
        }
        __syncthreads();
        mfma_store(ws, a, dis, M, n, it, tid);
    }
}

// ---------------- sliced aggregation phase (slice = it&3; GRID%4==0 keeps
// slice constant per block -> per-XCD L2 holds one 3.2 MB slice) -------------

static __device__ __forceinline__ void agg_phase(const int4* Ms4, const ushort* csr,
        const int* offs, const float* dis, const float* bias, int4* Hs4,
        int n, int bid, int tid) {
    int nI = ((n + 63) >> 6) * 4;
    for (int it = bid; it < nI; it += GRID) {
        int slice = it & 3;
        int node = (it >> 2) * 64 + (tid >> 2);
        if (node >= n) continue;
        int q = tid & 3;
        const int4* M = Ms4 + (size_t)slice * n * 4;
        int beg = offs[node], end = offs[node + 1];

        float acc[8];
        {
            int4 u = M[(size_t)node * 4 + q];
            const uint* w = (const uint*)&u;
#pragma unroll
            for (int k = 0; k < 4; ++k) { acc[2 * k] = bflo(w[k]); acc[2 * k + 1] = bfhi(w[k]); }
        }

        int ee = beg;
        for (; ee + 4 <= end; ee += 4) {
            int s0 = csr[ee], s1 = csr[ee + 1], s2 = csr[ee + 2], s3 = csr[ee + 3];
            int4 u0 = M[(size_t)s0 * 4 + q];
            int4 u1 = M[(size_t)s1 * 4 + q];
            int4 u2 = M[(size_t)s2 * 4 + q];
            int4 u3 = M[(size_t)s3 * 4 + q];
            upadd(acc, u0); upadd(acc, u1); upadd(acc, u2); upadd(acc, u3);
        }
        for (; ee < end; ++ee) {
            int4 u0 = M[(size_t)csr[ee] * 4 + q];
            upadd(acc, u0);
        }

        float dn = dis[node];
        const float2* b2 = (const float2*)bias + slice * 16 + q * 4;
        uint o[4];
#pragma unroll
        for (int k = 0; k < 4; ++k) {
            float2 bk = b2[k];
            float v0 = dn * acc[2 * k] + bk.x, v1 = dn * acc[2 * k + 1] + bk.y;
            v0 = v0 > 0.f ? v0 : 0.01f * v0;
            v1 = v1 > 0.f ? v1 : 0.01f * v1;
            o[k] = (uint)f2bf(v0) | ((uint)f2bf(v1) << 16);
        }
        Hs4[(size_t)slice * n * 4 + (size_t)node * 4 + q] = *(const int4*)o;
    }
}

// ---------------- the mega kernel ----------------

__global__ __launch_bounds__(TPB, 4) void mega_k(
        const float* __restrict__ x, const int* __restrict__ esrc,
        const int* __restrict__ edst,
        const float* __restrict__ W0f, const float* __restrict__ W1f,
        const float* __restrict__ W2f, const float* __restrict__ W3f,
        const float* __restrict__ b0, const float* __restrict__ b1,
        const float* __restrict__ b2, const float* __restrict__ b3,
        const float* __restrict__ lens_w, const float* __restrict__ lens_b,
        uint* gcnt, int* bcnt, int* gbase, int* gcur, int* offs, float* dis,
        uint* stage, ushort* csr, ushort* mbuf, ushort* hA, ushort* hB,
        ushort* WTs, float* outbuf, float* wcomb, float2* part, float* Lbuf,
        float* conc, float* logp, int n, int e, int ncls) {
    __shared__ SMem sm;
    const int bid = blockIdx.x;
    const int tid = threadIdx.x;
    const int NB = (n + 255) >> 8;       // 196 buckets
    const int EB = (e + 1023) >> 10;     // 782 edge tiles
    uint tgt = 0;

    // ---- phase 1: coarse histogram + weight prep + wcomb (independent) ----
    {
        int nI = EB + 256 + ncls;
        for (int it = bid; it < nI; it += GRID) {
            __syncthreads();
            if (it < EB) {
                sm.ha.h[tid] = 0;
                __syncthreads();
                int base = it * 1024;
#pragma unroll
                for (int k = 0; k < 4; ++k) {
                    int i = base + k * 256 + tid;
                    if (i < e) atomicAdd(&sm.ha.h[edst[i] >> 8], 1);
                }
                __syncthreads();
                if (sm.ha.h[tid]) atomicAdd(&bcnt[tid], sm.ha.h[tid]);
            } else if (it < EB + 256) {
                int wi = it - EB;
                const float* W = (wi >= 192) ? W3f : (wi >= 128) ? W2f
                               : (wi >= 64) ? W1f : W0f;
                ushort* outp = WTs + (size_t)(wi >> 6) * 16384;
                int idx = (wi & 63) * 256 + tid;
                int col = idx >> 7, k = idx & 127;
                float w = W[k * 128 + col];
                int byte = ((col * 128 + k) * 2) ^ ((col & 7) << 4);
                *(ushort*)((char*)outp + byte) = f2bf(w);
            } else {
                int c = it - EB - 256;
                float w = 0.f, g = 0.f, m = -1.f;
                if (tid < 128) { w = lens_w[c * 128 + tid]; g = fabsf(w); m = g; }
#pragma unroll
                for (int off = 32; off; off >>= 1) m = fmaxf(m, __shfl_xor(m, off));
                if (tid < 128 && (tid & 63) == 0) sm.wc.red[tid >> 6] = m;
                __syncthreads();
                if (tid < 128) {
                    m = fmaxf(sm.wc.red[0], sm.wc.red[1]);
                    wcomb[c * 128 + tid] = __expf((g - m) * (1.0f / 0.6f)) * w;
                }
            }
        }
    }
    gsync(gcnt, tgt += GRID);

    // ---- phase 2: scan buckets (block 0 only) ----
    if (bid == 0) {
        int v = (tid < NB) ? bcnt[tid] : 0;
        sm.sc.tmp[tid] = v;
        __syncthreads();
        int run = v;
        for (int off = 1; off < 256; off <<= 1) {
            int a = (tid >= off) ? sm.sc.tmp[tid - off] : 0;
            __syncthreads();
            run += a;
            sm.sc.tmp[tid] = run;
            __syncthreads();
        }
        if (tid < NB) { gbase[tid] = run - v; gcur[tid] = run - v; }
        if (tid == 0) gbase[NB] = e;
    }
    gsync(gcnt, tgt += GRID);

    // ---- phase 3: scatter edges into coarse buckets ----
    for (int it = bid; it < EB; it += GRID) {
        __syncthreads();
        sm.sa.h[tid] = 0;
        __syncthreads();
        int base = it * 1024;
        int r[4], bk[4];
        uint val[4];
#pragma unroll
        for (int k = 0; k < 4; ++k) {
            int i = base + k * 256 + tid;
            if (i < e) {
                int s = esrc[i], d = edst[i];
                bk[k] = d >> 8;
                val[k] = ((uint)(d & 255) << 16) | (uint)s;
                r[k] = atomicAdd(&sm.sa.h[bk[k]], 1);
            } else bk[k] = -1;
        }
        __syncthreads();
        if (sm.sa.h[tid]) sm.sa.lb[tid] = atomicAdd(&gcur[tid], sm.sa.h[tid]);
        __syncthreads();
#pragma unroll
        for (int k = 0; k < 4; ++k)
            if (bk[k] >= 0) stage[sm.sa.lb[bk[k]] + r[k]] = val[k];
    }
    gsync(gcnt, tgt += GRID);

    // ---- phase 4: per-bucket place (offs + dis + csr) ----
    for (int it = bid; it < NB; it += GRID) {
        __syncthreads();
        int e0 = gbase[it], e1 = gbase[it + 1];
        sm.pb.cnt[tid] = 0;
        __syncthreads();
        for (int i = e0 + tid; i < e1; i += 256) atomicAdd(&sm.pb.cnt[stage[i] >> 16], 1);
        __syncthreads();
        int v = sm.pb.cnt[tid];
        int run = v;
        sm.pb.tmp[tid] = run;
        __syncthreads();
        for (int off = 1; off < 256; off <<= 1) {
            int a = (tid >= off) ? sm.pb.tmp[tid - off] : 0;
            __syncthreads();
            run += a;
            sm.pb.tmp[tid] = run;
            __syncthreads();
        }
        int ex = e0 + run - v;
        int node = it * 256 + tid;
        if (node < n) {
            offs[node] = ex;
            dis[node] = rsqrtf((float)(v + 1));
        }
        sm.pb.cur[tid] = ex;
        __syncthreads();
        for (int i = e0 + tid; i < e1; i += 256) {
            uint w = stage[i];
            int slot = atomicAdd(&sm.pb.cur[w >> 16], 1);
            csr[slot] = (ushort)(w & 0xffffu);
        }
        if (it == 0 && tid == 0) offs[n] = e;
    }
    gsync(gcnt, tgt += GRID);

    // ---- 4 GCN layers ----
    gemm0_phase(sm.ws, x, WTs, dis, mbuf, n, bid, tid);
    gsync(gcnt, tgt += GRID);
    agg_phase((const int4*)mbuf, csr, offs, dis, b0, (int4*)hA, n, bid, tid);
    gsync(gcnt, tgt += GRID);
    gemm_phase(sm.ws, hA, WTs + 16384, dis, mbuf, n, bid, tid);
    gsync(gcnt, tgt += GRID);
    agg_phase((const int4*)mbuf, csr, offs, dis, b1, (int4*)hB, n, bid, tid);
    gsync(gcnt, tgt += GRID);
    gemm_phase(sm.ws, hB, WTs + 2 * 16384, dis, mbuf, n, bid, tid);
    gsync(gcnt, tgt += GRID);
    agg_phase((const int4*)mbuf, csr, offs, dis, b2, (int4*)hA, n, bid, tid);
    gsync(gcnt, tgt += GRID);
    gemm_phase(sm.ws, hA, WTs + 3 * 16384, dis, mbuf, n, bid, tid);
    gsync(gcnt, tgt += GRID);
    agg_phase((const int4*)mbuf, csr, offs, dis, b3, (int4*)hB, n, bid, tid);
    gsync(gcnt, tgt += GRID);

    // ---- epilogue: concepts + EntropyLinear ----
    {
        for (int i = tid; i < ncls * 128; i += TPB) {
            int c = i >> 7, d = i & 127;
            sm.ep.wcT[c * 128 + (d & 7) * 16 + (d >> 3)] = wcomb[i];
        }
        if (tid < ncls) sm.ep.lb[tid] = lens_b[tid];
        __syncthreads();
        const int4* Hs4 = (const int4*)hB;
        int nI = (n + 15) >> 4;
        for (int it = bid; it < nI; it += GRID) {
            int node = it * 16 + (tid >> 4);
            if (node >= n) continue;
            int li = tid & 15;
            int slice = li >> 2, q = li & 3;

            int4 u = Hs4[((size_t)slice * n + node) * 4 + q];
            float v[8];
            {
                const uint* w = (const uint*)&u;
#pragma unroll
                for (int k = 0; k < 4; ++k) { v[2 * k] = bflo(w[k]); v[2 * k + 1] = bfhi(w[k]); }
            }
            float m = v[0];
#pragma unroll
            for (int j = 1; j < 8; ++j) m = fmaxf(m, v[j]);
#pragma unroll
            for (int off = 8; off; off >>= 1) m = fmaxf(m, __shfl_xor(m, off));

            float c8[8];
#pragma unroll
            for (int j = 0; j < 8; ++j) c8[j] = __expf(v[j] - m);

            float4* cc = (float4*)(conc + (size_t)node * 128 + li * 8);
            cc[0] = make_float4(c8[0], c8[1], c8[2], c8[3]);
            cc[1] = make_float4(c8[4], c8[5], c8[6], c8[7]);

            for (int c = 0; c < ncls; ++c) {
                float pv = 0.f;
#pragma unroll
                for (int j = 0; j < 8; ++j) pv += c8[j] * sm.ep.wcT[c * 128 + j * 16 + li];
#pragma unroll
                for (int off = 8; off; off >>= 1) pv += __shfl_xor(pv, off);
                if (li == 0) outbuf[(size_t)c * n + node] = pv + sm.ep.lb[c];
            }
        }
    }
    gsync(gcnt, tgt += GRID);

    // ---- lsm1: per-chunk online logsumexp ----
    {
        const int nch = 64;
        const int chunk = (n + nch - 1) / nch;
        int nI = nch * ncls;
        for (int it = bid; it < nI; it += GRID) {
            __syncthreads();
            int cx = it & 63, c = it >> 6;
            const float* col = outbuf + (size_t)c * n;
            int i0 = cx * chunk;
            int i1 = min(n, i0 + chunk);
            float m = -3.0e38f, s = 0.f;
            for (int i = i0 + tid; i < i1; i += TPB) {
                float xv = col[i];
                if (xv > m) { s = s * __expf(m - xv) + 1.f; m = xv; }
                else        { s += __expf(xv - m); }
            }
#pragma unroll
            for (int off = 32; off; off >>= 1) {
                float m2 = __shfl_xor(m, off), s2 = __shfl_xor(s, off);
                float mm = fmaxf(m, m2);
                s = s * __expf(m - mm) + s2 * __expf(m2 - mm);
                m = mm;
            }
            int lane = tid & 63, w = tid >> 6;
            if (lane == 0) sm.r1.red[w] = make_float2(m, s);
            __syncthreads();
            if (tid == 0) {
                m = sm.r1.red[0].x; s = sm.r1.red[0].y;
                for (int k = 1; k < 4; ++k) {
                    float m2 = sm.r1.red[k].x, s2 = sm.r1.red[k].y;
                    float mm = fmaxf(m, m2);
                    s = s * __expf(m - mm) + s2 * __expf(m2 - mm);
                    m = mm;
                }
                part[(size_t)c * nch + cx] = make_float2(m, s);
            }
        }
    }
    gsync(gcnt, tgt += GRID);

    // ---- lsm2: merge partials (block 0 only) ----
    if (bid == 0 && tid < 64) {
        int c = tid;
        if (c < ncls) {
            float m = -3.0e38f, s = 0.f;
            for (int k = 0; k < 64; ++k) {
                float2 pp = part[(size_t)c * 64 + k];
                float mm = fmaxf(m, pp.x);
                s = s * __expf(m - mm) + pp.y * __expf(pp.x - mm);
                m = mm;
            }
            Lbuf[c] = m + __logf(s);
        }
    }
    gsync(gcnt, tgt += GRID);

    // ---- lsm3: subtract ----
    {
        if (tid < ncls) sm.Ls[tid] = Lbuf[tid];
        __syncthreads();
        int nI = (n + 255) >> 8;
        for (int it = bid; it < nI; it += GRID) {
            int i = it * 256 + tid;
            if (i < n)
                for (int c = 0; c < ncls; ++c)
                    logp[(size_t)i * ncls + c] = outbuf[(size_t)c * n + i] - sm.Ls[c];
        }
    }
}

// ---------------- launch ----------------

extern "C" void kernel_launch(void* const* d_in, const int* in_sizes, int n_in,
                              void* d_out, int out_size, void* d_ws, size_t ws_size,
                              hipStream_t stream) {
    const int N = in_sizes[0] / DIMF;     // 50000
    const int E = in_sizes[1] / 2;        // 800000
    const int C = in_sizes[10] / DIMF;    // 10

    const float* x    = (const float*)d_in[0];
    const int*   ei   = (const int*)d_in[1];
    const int*   esrc = ei;
    const int*   edst = ei + E;
    const float* W0 = (const float*)d_in[2];
    const float* W1 = (const float*)d_in[4];
    const float* W2 = (const float*)d_in[6];
    const float* W3 = (const float*)d_in[8];
    const float* b0 = (const float*)d_in[3];
    const float* b1 = (const float*)d_in[5];
    const float* b2 = (const float*)d_in[7];
    const float* b3 = (const float*)d_in[9];
    const float* lens_w = (const float*)d_in[10];
    const float* lens_b = (const float*)d_in[11];

    float* out_concepts = (float*)d_out;                     // N*128
    float* out_logp     = (float*)d_out + (size_t)N * DIMF;  // N*C

    char* p = (char*)d_ws;
    auto alloc = [&](size_t bytes) -> void* {
        void* r = (void*)p;
        p += (bytes + 255) & ~(size_t)255;
        return r;
    };
    uint*   gcnt   = (uint*)alloc(256 * 4);                  // barrier counter
    int*    bcnt   = (int*)alloc(256 * 4);                   // contiguous w/ gcnt
    int*    gbase  = (int*)alloc(257 * 4);
    int*    gcur   = (int*)alloc(256 * 4);
    int*    offs   = (int*)alloc(((size_t)N + 1) * 4);
    float*  dis    = (float*)alloc((size_t)N * 4);
    uint*   stage  = (uint*)alloc((size_t)E * 4);
    ushort* csr    = (ushort*)alloc((size_t)E * 2);
    ushort* mbuf   = (ushort*)alloc((size_t)N * DIMF * 2);   // sliced [4][N][32]
    ushort* hA     = (ushort*)alloc((size_t)N * DIMF * 2);   // sliced
    ushort* hB     = (ushort*)alloc((size_t)N * DIMF * 2);   // sliced
    ushort* WTs    = (ushort*)alloc((size_t)4 * 16384 * 2);
    float*  outbuf = (float*)alloc((size_t)C * N * 4);
    float*  wcomb  = (float*)alloc((size_t)C * DIMF * 4);
    float2* part   = (float2*)alloc((size_t)C * 64 * 8);
    float*  Lbuf   = (float*)alloc(64 * 4);

    // zero barrier counter + bucket counts (gcnt and bcnt are adjacent)
    hipMemsetAsync(gcnt, 0, 2048, stream);

    mega_k<<<GRID, TPB, 0, stream>>>(
        x, esrc, edst, W0, W1, W2, W3, b0, b1, b2, b3, lens_w, lens_b,
        gcnt, bcnt, gbase, gcur, offs, dis, stage, csr, mbuf, hA, hB,
        WTs, outbuf, wcomb, part, Lbuf, out_concepts, out_logp, N, E, C);
}

// Round 2
// 285.211 us; speedup vs baseline: 5.4757x; 5.4757x over previous
//
#include <hip/hip_runtime.h>

// GCN (4 layers, DIM=128) + concepts + EntropyLinear + log_softmax over nodes.
// R8: persistent mega-kernel with HIERARCHICAL XCD-aware grid barrier.
//     R7's flat barrier cost ~95us each: every block's RELEASE/ACQUIRE emitted
//     a full per-XCD L2 writeback/invalidate walk (buffer_wbl2/buffer_inv sc1)
//     -> 2048 L2 walks per barrier. Now: per-XCD arrive counters (relaxed),
//     exactly ONE release (wbl2) + ONE L2-inv per XCD per barrier (the last
//     arriver / leader), followers take a cheap L1-only buffer_inv. XCD id via
//     s_getreg(HW_REG_XCC_ID); populations discovered dynamically at start.

#define DIMF 128
#define GRID 1024
#define TPB  256

typedef __bf16 bf16x8 __attribute__((ext_vector_type(8)));
typedef float f32x4 __attribute__((ext_vector_type(4)));

static __device__ __forceinline__ ushort f2bf(float f) {
    uint u = __float_as_uint(f);
    u += 0x7fffu + ((u >> 16) & 1u);     // round-nearest-even
    return (ushort)(u >> 16);
}
static __device__ __forceinline__ float bflo(uint u) { return __uint_as_float(u << 16); }
static __device__ __forceinline__ float bfhi(uint u) { return __uint_as_float(u & 0xffff0000u); }

static __device__ __forceinline__ void upadd(float* acc, const int4& u) {
    const uint* w = (const uint*)&u;
#pragma unroll
    for (int k = 0; k < 4; ++k) {
        acc[2 * k]     += bflo(w[k]);
        acc[2 * k + 1] += bfhi(w[k]);
    }
}

// ---------------- LDS union (32 KB; 4 blocks/CU = 128 KB of 160 KB) ---------

union SMem {
    ushort ws[16384];                                    // gemm W tile (32 KB)
    struct { int h[256]; } ha;                           // histA
    struct { int tmp[256]; } sc;                         // scanNB
    struct { int h[256]; int lb[256]; } sa;              // scatA
    struct { int cnt[256]; int cur[256]; int tmp[256]; } pb;  // phaseB
    struct { float wcT[1280]; float lb[16]; } ep;        // epilogue
    struct { float2 red[4]; } r1;                        // lsm1
    struct { float red[2]; } wc;                         // wcomb
    struct { float2 red2[176]; float Ls[16]; } l3;       // lsm3 (fused lsm2)
};

// ---------------- hierarchical grid barrier ----------------
// counter block cb (uint*), all zeroed by host:
//   cb[0]            root0 : startup population barrier
//   cb[32]           root  : main barrier (sum of pops per round)
//   cb[64..79]       axc0  : per-XCD population
//   cb[128+32*x]     axc   : per-XCD monotonic arrive counter (own cacheline)
//   cb[640+32*x]     xdone : per-XCD round-complete flag   (own cacheline)

static __device__ __forceinline__ void gsync(uint* cb, uint r, uint& pop, uint xcc) {
    __syncthreads();   // all waves done; vmcnt drained -> writes are in local L2
    if (threadIdx.x == 0) {
        uint* axc   = cb + 128 + 32 * xcc;
        uint* xdone = cb + 640 + 32 * xcc;
        uint* root  = cb + 32;
        if (pop == 0) {   // lazy: resolve this XCD's population (startup done long ago)
            while (__hip_atomic_load(cb, __ATOMIC_RELAXED, __HIP_MEMORY_SCOPE_AGENT) < (uint)GRID)
                __builtin_amdgcn_s_sleep(2);
            pop = __hip_atomic_load(cb + 64 + xcc, __ATOMIC_RELAXED, __HIP_MEMORY_SCOPE_AGENT);
        }
        uint v = __hip_atomic_fetch_add(axc, 1u, __ATOMIC_RELAXED, __HIP_MEMORY_SCOPE_AGENT) + 1;
        if (v == r * pop) {
            // last arriver on this XCD: ONE release (L2 writeback) + root signal
            __hip_atomic_fetch_add(root, pop, __ATOMIC_RELEASE, __HIP_MEMORY_SCOPE_AGENT);
            while (__hip_atomic_load(root, __ATOMIC_RELAXED, __HIP_MEMORY_SCOPE_AGENT) < r * (uint)GRID)
                __builtin_amdgcn_s_sleep(2);
            // ONE L2 (+L1) invalidate for this XCD, completed before flagging
            asm volatile("buffer_inv\n\tbuffer_inv sc1\n\ts_waitcnt vmcnt(0)" ::: "memory");
            __hip_atomic_store(xdone, r, __ATOMIC_RELAXED, __HIP_MEMORY_SCOPE_AGENT);
        } else {
            while (__hip_atomic_load(xdone, __ATOMIC_RELAXED, __HIP_MEMORY_SCOPE_AGENT) < r)
                __builtin_amdgcn_s_sleep(2);
            // L2 already invalidated by leader; L1 (per-CU) flash-invalidate only
            asm volatile("buffer_inv\n\ts_waitcnt vmcnt(0)" ::: "memory");
        }
    }
    __syncthreads();
}

// ---------------- GEMM helpers ----------------

static __device__ __forceinline__ void ldws(ushort* ws, const ushort* WTsL, int tid) {
    const int4* src = (const int4*)WTsL;
    int4* dst = (int4*)ws;
#pragma unroll
    for (int i = 0; i < 8; ++i) dst[tid + 256 * i] = src[tid + 256 * i];
}

static __device__ __forceinline__ void mfma_store(const ushort* ws, const int4* a,
        const float* dis, ushort* M, int nrows, int it, int tid) {
    int wave = tid >> 6, lane = tid & 63;
    int lo = lane & 15, hi = lane >> 4;
    f32x4 acc[8];
#pragma unroll
    for (int ct = 0; ct < 8; ++ct) acc[ct] = (f32x4){0.f, 0.f, 0.f, 0.f};
#pragma unroll
    for (int kc = 0; kc < 4; ++kc) {
        bf16x8 av = __builtin_bit_cast(bf16x8, a[kc]);
#pragma unroll
        for (int ct = 0; ct < 8; ++ct) {
            int col = ct * 16 + lo;
            int byte = (col * 256 + kc * 64 + hi * 16) ^ ((col & 7) << 4);
            bf16x8 bv = *(const bf16x8*)((const char*)ws + byte);
            acc[ct] = __builtin_amdgcn_mfma_f32_16x16x32_bf16(av, bv, acc[ct], 0, 0, 0);
        }
    }
    int rbase = it * 64 + wave * 16 + hi * 4;
#pragma unroll
    for (int r = 0; r < 4; ++r) {
        int orow = rbase + r;
        if (orow < nrows) {
            float dn = dis[orow];
#pragma unroll
            for (int ct = 0; ct < 8; ++ct)
                M[((size_t)(ct >> 1) * nrows + orow) * 32 + (ct & 1) * 16 + lo]
                    = f2bf(dn * acc[ct][r]);
        }
    }
}

static __device__ __forceinline__ void gemm_phase(ushort* ws, const ushort* H,
        const ushort* WTsL, const float* dis, ushort* M, int n, int bid, int tid) {
    int nI = (n + 63) >> 6;
    for (int it = bid; it < nI; it += GRID) {
        __syncthreads();                 // prev item's ws reads done
        ldws(ws, WTsL, tid);
        int wave = tid >> 6, lane = tid & 63;
        int lo = lane & 15, hi = lane >> 4;
        int arow = it * 64 + wave * 16 + lo;
        bool inb = arow < n;
        int4 a[4];
        const int4* h4 = (const int4*)H;    // sliced: [slice][node][4 x int4]
#pragma unroll
        for (int kc = 0; kc < 4; ++kc) {
            int4 z = {0, 0, 0, 0};
            a[kc] = inb ? h4[((size_t)kc * n + arow) * 4 + hi] : z;
        }
        __syncthreads();
        mfma_store(ws, a, dis, M, n, it, tid);
    }
}

static __device__ __forceinline__ void gemm0_phase(ushort* ws, const float* X,
        const ushort* WTsL, const float* dis, ushort* M, int n, int bid, int tid) {
    int nI = (n + 63) >> 6;
    for (int it = bid; it < nI; it += GRID) {
        __syncthreads();
        ldws(ws, WTsL, tid);
        int wave = tid >> 6, lane = tid & 63;
        int lo = lane & 15, hi = lane >> 4;
        int arow = it * 64 + wave * 16 + lo;
        bool inb = arow < n;
        int4 a[4];
        const float4* x4 = (const float4*)X;
#pragma unroll
        for (int kc = 0; kc < 4; ++kc) {
            float4 f0 = make_float4(0.f, 0.f, 0.f, 0.f), f1 = f0;
            if (inb) {
                f0 = x4[(size_t)arow * 32 + kc * 8 + hi * 2];
                f1 = x4[(size_t)arow * 32 + kc * 8 + hi * 2 + 1];
            }
            ushort u[8] = { f2bf(f0.x), f2bf(f0.y), f2bf(f0.z), f2bf(f0.w),
                            f2bf(f1.x), f2bf(f1.y), f2bf(f1.z), f2bf(f1.w) };
            a[kc] = *(const int4*)u;
        }
        __syncthreads();
        mfma_store(ws, a, dis, M, n, it, tid);
    }
}

// ---------------- sliced aggregation phase ----------------

static __device__ __forceinline__ void agg_phase(const int4* Ms4, const ushort* csr,
        const int* offs, const float* dis, const float* bias, int4* Hs4,
        int n, int bid, int tid) {
    int nI = ((n + 63) >> 6) * 4;
    for (int it = bid; it < nI; it += GRID) {
        int slice = it & 3;
        int node = (it >> 2) * 64 + (tid >> 2);
        if (node >= n) continue;
        int q = tid & 3;
        const int4* M = Ms4 + (size_t)slice * n * 4;
        int beg = offs[node], end = offs[node + 1];

        float acc[8];
        {
            int4 u = M[(size_t)node * 4 + q];
            const uint* w = (const uint*)&u;
#pragma unroll
            for (int k = 0; k < 4; ++k) { acc[2 * k] = bflo(w[k]); acc[2 * k + 1] = bfhi(w[k]); }
        }

        int ee = beg;
        for (; ee + 4 <= end; ee += 4) {
            int s0 = csr[ee], s1 = csr[ee + 1], s2 = csr[ee + 2], s3 = csr[ee + 3];
            int4 u0 = M[(size_t)s0 * 4 + q];
            int4 u1 = M[(size_t)s1 * 4 + q];
            int4 u2 = M[(size_t)s2 * 4 + q];
            int4 u3 = M[(size_t)s3 * 4 + q];
            upadd(acc, u0); upadd(acc, u1); upadd(acc, u2); upadd(acc, u3);
        }
        for (; ee < end; ++ee) {
            int4 u0 = M[(size_t)csr[ee] * 4 + q];
            upadd(acc, u0);
        }

        float dn = dis[node];
        const float2* b2 = (const float2*)bias + slice * 16 + q * 4;
        uint o[4];
#pragma unroll
        for (int k = 0; k < 4; ++k) {
            float2 bk = b2[k];
            float v0 = dn * acc[2 * k] + bk.x, v1 = dn * acc[2 * k + 1] + bk.y;
            v0 = v0 > 0.f ? v0 : 0.01f * v0;
            v1 = v1 > 0.f ? v1 : 0.01f * v1;
            o[k] = (uint)f2bf(v0) | ((uint)f2bf(v1) << 16);
        }
        Hs4[(size_t)slice * n * 4 + (size_t)node * 4 + q] = *(const int4*)o;
    }
}

// ---------------- the mega kernel ----------------

__global__ __launch_bounds__(TPB, 4) void mega_k(
        const float* __restrict__ x, const int* __restrict__ esrc,
        const int* __restrict__ edst,
        const float* __restrict__ W0f, const float* __restrict__ W1f,
        const float* __restrict__ W2f, const float* __restrict__ W3f,
        const float* __restrict__ b0, const float* __restrict__ b1,
        const float* __restrict__ b2, const float* __restrict__ b3,
        const float* __restrict__ lens_w, const float* __restrict__ lens_b,
        uint* cb, int* bcnt, int* gbase, int* gcur, int* offs, float* dis,
        uint* stage, ushort* csr, ushort* mbuf, ushort* hA, ushort* hB,
        ushort* WTs, float* outbuf, float* wcomb, float2* part,
        float* conc, float* logp, int n, int e, int ncls) {
    __shared__ SMem sm;
    const int bid = blockIdx.x;
    const int tid = threadIdx.x;
    const int NB = (n + 255) >> 8;       // 196 buckets
    const int EB = (e + 1023) >> 10;     // 782 edge tiles
    uint rr = 0;

    // ---- startup: register this block's XCD; population resolved lazily ----
    uint xcc;
    asm volatile("s_getreg_b32 %0, hwreg(HW_REG_XCC_ID)" : "=s"(xcc));
    xcc &= 15;
    uint pop = 0;
    if (tid == 0) {
        __hip_atomic_fetch_add(cb + 64 + xcc, 1u, __ATOMIC_RELAXED, __HIP_MEMORY_SCOPE_AGENT);
        asm volatile("s_waitcnt vmcnt(0)" ::: "memory");   // order: pop add before root0 add
        __hip_atomic_fetch_add(cb, 1u, __ATOMIC_RELAXED, __HIP_MEMORY_SCOPE_AGENT);
    }

    // ---- phase 1: coarse histogram + weight prep + wcomb (independent) ----
    {
        int nI = EB + 256 + ncls;
        for (int it = bid; it < nI; it += GRID) {
            __syncthreads();
            if (it < EB) {
                sm.ha.h[tid] = 0;
                __syncthreads();
                int base = it * 1024;
#pragma unroll
                for (int k = 0; k < 4; ++k) {
                    int i = base + k * 256 + tid;
                    if (i < e) atomicAdd(&sm.ha.h[edst[i] >> 8], 1);
                }
                __syncthreads();
                if (sm.ha.h[tid]) atomicAdd(&bcnt[tid], sm.ha.h[tid]);
            } else if (it < EB + 256) {
                int wi = it - EB;
                const float* W = (wi >= 192) ? W3f : (wi >= 128) ? W2f
                               : (wi >= 64) ? W1f : W0f;
                ushort* outp = WTs + (size_t)(wi >> 6) * 16384;
                int idx = (wi & 63) * 256 + tid;
                int col = idx >> 7, k = idx & 127;
                float w = W[k * 128 + col];
                int byte = ((col * 128 + k) * 2) ^ ((col & 7) << 4);
                *(ushort*)((char*)outp + byte) = f2bf(w);
            } else {
                int c = it - EB - 256;
                float w = 0.f, g = 0.f, m = -1.f;
                if (tid < 128) { w = lens_w[c * 128 + tid]; g = fabsf(w); m = g; }
#pragma unroll
                for (int off = 32; off; off >>= 1) m = fmaxf(m, __shfl_xor(m, off));
                if (tid < 128 && (tid & 63) == 0) sm.wc.red[tid >> 6] = m;
                __syncthreads();
                if (tid < 128) {
                    m = fmaxf(sm.wc.red[0], sm.wc.red[1]);
                    wcomb[c * 128 + tid] = __expf((g - m) * (1.0f / 0.6f)) * w;
                }
            }
        }
    }
    gsync(cb, ++rr, pop, xcc);

    // ---- phase 2: scan buckets (block 0 only) ----
    if (bid == 0) {
        int v = (tid < NB) ? bcnt[tid] : 0;
        sm.sc.tmp[tid] = v;
        __syncthreads();
        int run = v;
        for (int off = 1; off < 256; off <<= 1) {
            int a = (tid >= off) ? sm.sc.tmp[tid - off] : 0;
            __syncthreads();
            run += a;
            sm.sc.tmp[tid] = run;
            __syncthreads();
        }
        if (tid < NB) { gbase[tid] = run - v; gcur[tid] = run - v; }
        if (tid == 0) gbase[NB] = e;
    }
    gsync(cb, ++rr, pop, xcc);

    // ---- phase 3: scatter edges into coarse buckets ----
    for (int it = bid; it < EB; it += GRID) {
        __syncthreads();
        sm.sa.h[tid] = 0;
        __syncthreads();
        int base = it * 1024;
        int r[4], bk[4];
        uint val[4];
#pragma unroll
        for (int k = 0; k < 4; ++k) {
            int i = base + k * 256 + tid;
            if (i < e) {
                int s = esrc[i], d = edst[i];
                bk[k] = d >> 8;
                val[k] = ((uint)(d & 255) << 16) | (uint)s;
                r[k] = atomicAdd(&sm.sa.h[bk[k]], 1);
            } else bk[k] = -1;
        }
        __syncthreads();
        if (sm.sa.h[tid]) sm.sa.lb[tid] = atomicAdd(&gcur[tid], sm.sa.h[tid]);
        __syncthreads();
#pragma unroll
        for (int k = 0; k < 4; ++k)
            if (bk[k] >= 0) stage[sm.sa.lb[bk[k]] + r[k]] = val[k];
    }
    gsync(cb, ++rr, pop, xcc);

    // ---- phase 4: per-bucket place (offs + dis + csr) ----
    for (int it = bid; it < NB; it += GRID) {
        __syncthreads();
        int e0 = gbase[it], e1 = gbase[it + 1];
        sm.pb.cnt[tid] = 0;
        __syncthreads();
        for (int i = e0 + tid; i < e1; i += 256) atomicAdd(&sm.pb.cnt[stage[i] >> 16], 1);
        __syncthreads();
        int v = sm.pb.cnt[tid];
        int run = v;
        sm.pb.tmp[tid] = run;
        __syncthreads();
        for (int off = 1; off < 256; off <<= 1) {
            int a = (tid >= off) ? sm.pb.tmp[tid - off] : 0;
            __syncthreads();
            run += a;
            sm.pb.tmp[tid] = run;
            __syncthreads();
        }
        int ex = e0 + run - v;
        int node = it * 256 + tid;
        if (node < n) {
            offs[node] = ex;
            dis[node] = rsqrtf((float)(v + 1));
        }
        sm.pb.cur[tid] = ex;
        __syncthreads();
        for (int i = e0 + tid; i < e1; i += 256) {
            uint w = stage[i];
            int slot = atomicAdd(&sm.pb.cur[w >> 16], 1);
            csr[slot] = (ushort)(w & 0xffffu);
        }
        if (it == 0 && tid == 0) offs[n] = e;
    }
    gsync(cb, ++rr, pop, xcc);

    // ---- 4 GCN layers ----
    gemm0_phase(sm.ws, x, WTs, dis, mbuf, n, bid, tid);
    gsync(cb, ++rr, pop, xcc);
    agg_phase((const int4*)mbuf, csr, offs, dis, b0, (int4*)hA, n, bid, tid);
    gsync(cb, ++rr, pop, xcc);
    gemm_phase(sm.ws, hA, WTs + 16384, dis, mbuf, n, bid, tid);
    gsync(cb, ++rr, pop, xcc);
    agg_phase((const int4*)mbuf, csr, offs, dis, b1, (int4*)hB, n, bid, tid);
    gsync(cb, ++rr, pop, xcc);
    gemm_phase(sm.ws, hB, WTs + 2 * 16384, dis, mbuf, n, bid, tid);
    gsync(cb, ++rr, pop, xcc);
    agg_phase((const int4*)mbuf, csr, offs, dis, b2, (int4*)hA, n, bid, tid);
    gsync(cb, ++rr, pop, xcc);
    gemm_phase(sm.ws, hA, WTs + 3 * 16384, dis, mbuf, n, bid, tid);
    gsync(cb, ++rr, pop, xcc);
    agg_phase((const int4*)mbuf, csr, offs, dis, b3, (int4*)hB, n, bid, tid);
    gsync(cb, ++rr, pop, xcc);

    // ---- epilogue: concepts + EntropyLinear ----
    {
        for (int i = tid; i < ncls * 128; i += TPB) {
            int c = i >> 7, d = i & 127;
            sm.ep.wcT[c * 128 + (d & 7) * 16 + (d >> 3)] = wcomb[i];
        }
        if (tid < ncls) sm.ep.lb[tid] = lens_b[tid];
        __syncthreads();
        const int4* Hs4 = (const int4*)hB;
        int nI = (n + 15) >> 4;
        for (int it = bid; it < nI; it += GRID) {
            int node = it * 16 + (tid >> 4);
            if (node >= n) continue;
            int li = tid & 15;
            int slice = li >> 2, q = li & 3;

            int4 u = Hs4[((size_t)slice * n + node) * 4 + q];
            float v[8];
            {
                const uint* w = (const uint*)&u;
#pragma unroll
                for (int k = 0; k < 4; ++k) { v[2 * k] = bflo(w[k]); v[2 * k + 1] = bfhi(w[k]); }
            }
            float m = v[0];
#pragma unroll
            for (int j = 1; j < 8; ++j) m = fmaxf(m, v[j]);
#pragma unroll
            for (int off = 8; off; off >>= 1) m = fmaxf(m, __shfl_xor(m, off));

            float c8[8];
#pragma unroll
            for (int j = 0; j < 8; ++j) c8[j] = __expf(v[j] - m);

            float4* cc = (float4*)(conc + (size_t)node * 128 + li * 8);
            cc[0] = make_float4(c8[0], c8[1], c8[2], c8[3]);
            cc[1] = make_float4(c8[4], c8[5], c8[6], c8[7]);

            for (int c = 0; c < ncls; ++c) {
                float pv = 0.f;
#pragma unroll
                for (int j = 0; j < 8; ++j) pv += c8[j] * sm.ep.wcT[c * 128 + j * 16 + li];
#pragma unroll
                for (int off = 8; off; off >>= 1) pv += __shfl_xor(pv, off);
                if (li == 0) outbuf[(size_t)c * n + node] = pv + sm.ep.lb[c];
            }
        }
    }
    gsync(cb, ++rr, pop, xcc);

    // ---- lsm1: per-chunk online logsumexp ----
    {
        const int nch = 64;
        const int chunk = (n + nch - 1) / nch;
        int nI = nch * ncls;
        for (int it = bid; it < nI; it += GRID) {
            __syncthreads();
            int cx = it & 63, c = it >> 6;
            const float* col = outbuf + (size_t)c * n;
            int i0 = cx * chunk;
            int i1 = min(n, i0 + chunk);
            float m = -3.0e38f, s = 0.f;
            for (int i = i0 + tid; i < i1; i += TPB) {
                float xv = col[i];
                if (xv > m) { s = s * __expf(m - xv) + 1.f; m = xv; }
                else        { s += __expf(xv - m); }
            }
#pragma unroll
            for (int off = 32; off; off >>= 1) {
                float m2 = __shfl_xor(m, off), s2 = __shfl_xor(s, off);
                float mm = fmaxf(m, m2);
                s = s * __expf(m - mm) + s2 * __expf(m2 - mm);
                m = mm;
            }
            int lane = tid & 63, w = tid >> 6;
            if (lane == 0) sm.r1.red[w] = make_float2(m, s);
            __syncthreads();
            if (tid == 0) {
                m = sm.r1.red[0].x; s = sm.r1.red[0].y;
                for (int k = 1; k < 4; ++k) {
                    float m2 = sm.r1.red[k].x, s2 = sm.r1.red[k].y;
                    float mm = fmaxf(m, m2);
                    s = s * __expf(m - mm) + s2 * __expf(m2 - mm);
                    m = mm;
                }
                part[(size_t)c * nch + cx] = make_float2(m, s);
            }
        }
    }
    gsync(cb, ++rr, pop, xcc);

    // ---- lsm3: redundant per-block merge of partials (fused lsm2) + subtract ----
    {
        int c = tid >> 4, j = tid & 15;
        if (tid < ncls * 16) {
            float m = -3.0e38f, s = 0.f;
#pragma unroll
            for (int k = j * 4; k < j * 4 + 4; ++k) {
                float2 pp = part[(size_t)c * 64 + k];
                float mm = fmaxf(m, pp.x);
                s = s * __expf(m - mm) + pp.y * __expf(pp.x - mm);
                m = mm;
            }
            sm.l3.red2[c * 16 + j] = make_float2(m, s);
        }
        __syncthreads();
        if (tid < ncls) {
            float m = -3.0e38f, s = 0.f;
            for (int k = 0; k < 16; ++k) {
                float2 pp = sm.l3.red2[tid * 16 + k];
                float mm = fmaxf(m, pp.x);
                s = s * __expf(m - mm) + pp.y * __expf(pp.x - mm);
                m = mm;
            }
            sm.l3.Ls[tid] = m + __logf(s);
        }
        __syncthreads();
        int nI = (n + 255) >> 8;
        for (int it = bid; it < nI; it += GRID) {
            int i = it * 256 + tid;
            if (i < n)
                for (int c2 = 0; c2 < ncls; ++c2)
                    logp[(size_t)i * ncls + c2] = outbuf[(size_t)c2 * n + i] - sm.l3.Ls[c2];
        }
    }
}

// ---------------- launch ----------------

extern "C" void kernel_launch(void* const* d_in, const int* in_sizes, int n_in,
                              void* d_out, int out_size, void* d_ws, size_t ws_size,
                              hipStream_t stream) {
    const int N = in_sizes[0] / DIMF;     // 50000
    const int E = in_sizes[1] / 2;        // 800000
    const int C = in_sizes[10] / DIMF;    // 10

    const float* x    = (const float*)d_in[0];
    const int*   ei   = (const int*)d_in[1];
    const int*   esrc = ei;
    const int*   edst = ei + E;
    const float* W0 = (const float*)d_in[2];
    const float* W1 = (const float*)d_in[4];
    const float* W2 = (const float*)d_in[6];
    const float* W3 = (const float*)d_in[8];
    const float* b0 = (const float*)d_in[3];
    const float* b1 = (const float*)d_in[5];
    const float* b2 = (const float*)d_in[7];
    const float* b3 = (const float*)d_in[9];
    const float* lens_w = (const float*)d_in[10];
    const float* lens_b = (const float*)d_in[11];

    float* out_concepts = (float*)d_out;                     // N*128
    float* out_logp     = (float*)d_out + (size_t)N * DIMF;  // N*C

    char* p = (char*)d_ws;
    auto alloc = [&](size_t bytes) -> void* {
        void* r = (void*)p;
        p += (bytes + 255) & ~(size_t)255;
        return r;
    };
    uint*   cb     = (uint*)alloc(8192);                     // barrier counters
    int*    bcnt   = (int*)alloc(256 * 4);                   // contiguous w/ cb
    int*    gbase  = (int*)alloc(257 * 4);
    int*    gcur   = (int*)alloc(256 * 4);
    int*    offs   = (int*)alloc(((size_t)N + 1) * 4);
    float*  dis    = (float*)alloc((size_t)N * 4);
    uint*   stage  = (uint*)alloc((size_t)E * 4);
    ushort* csr    = (ushort*)alloc((size_t)E * 2);
    ushort* mbuf   = (ushort*)alloc((size_t)N * DIMF * 2);   // sliced [4][N][32]
    ushort* hA     = (ushort*)alloc((size_t)N * DIMF * 2);   // sliced
    ushort* hB     = (ushort*)alloc((size_t)N * DIMF * 2);   // sliced
    ushort* WTs    = (ushort*)alloc((size_t)4 * 16384 * 2);
    float*  outbuf = (float*)alloc((size_t)C * N * 4);
    float*  wcomb  = (float*)alloc((size_t)C * DIMF * 4);
    float2* part   = (float2*)alloc((size_t)C * 64 * 8);

    // zero barrier counters + bucket counts (cb and bcnt are adjacent)
    hipMemsetAsync(cb, 0, 8192 + 1024, stream);

    mega_k<<<GRID, TPB, 0, stream>>>(
        x, esrc, edst, W0, W1, W2, W3, b0, b1, b2, b3, lens_w, lens_b,
        cb, bcnt, gbase, gcur, offs, dis, stage, csr, mbuf, hA, hB,
        WTs, outbuf, wcomb, part, out_concepts, out_logp, N, E, C);
}